// Round 16
// baseline (203.492 us; speedup 1.0000x reference)
//
#include <hip/hip_runtime.h>
#include <hip/hip_bf16.h>
#include <math.h>

#define SEQ 2048
#define DM 1024
#define NH 16
#define DKV 64
#define MTOT 4096   /* BATCH*SEQ */
#define PST2 72     /* P-tile LDS row stride in shorts (64 + 8 pad) */

typedef __attribute__((ext_vector_type(8))) short bf16x8;
typedef __attribute__((ext_vector_type(4))) short s16x4;
typedef __attribute__((ext_vector_type(4))) float f32x4;
typedef unsigned short ushort_t;

__device__ __forceinline__ short f2bf(float f) {
    union { float f; unsigned u; } v; v.f = f;
    unsigned r = v.u + 0x7fffu + ((v.u >> 16) & 1u);
    return (short)(r >> 16);
}

__device__ __forceinline__ bf16x8 cvt8(f32x4 a, f32x4 b) {
    union { __hip_bfloat162 h[4]; bf16x8 v; } u;
    u.h[0] = __float22bfloat162_rn(float2{a[0], a[1]});
    u.h[1] = __float22bfloat162_rn(float2{a[2], a[3]});
    u.h[2] = __float22bfloat162_rn(float2{b[0], b[1]});
    u.h[3] = __float22bfloat162_rn(float2{b[2], b[3]});
    return u.v;
}

__device__ __forceinline__ s16x4 cvt4(float a, float b, float c, float d) {
    union { __hip_bfloat162 h[2]; s16x4 v; } u;
    u.h[0] = __float22bfloat162_rn(float2{a, b});
    u.h[1] = __float22bfloat162_rn(float2{c, d});
    return u.v;
}

// async global->LDS, 16B per lane. LDS dest = wave-uniform base + lane*16.
__device__ __forceinline__ void gload_lds16(const void* g, void* l) {
    __builtin_amdgcn_global_load_lds(
        (const __attribute__((address_space(1))) unsigned int*)g,
        (__attribute__((address_space(3))) unsigned int*)l, 16, 0, 0);
}

// ---------------- fused prep: RoPE tables + wo + Wqkv fuse + x convert, one launch ----------------
// blocks [0,256): cos/sin tables (fp32)
// blocks [256,768): Wob = bf16(wo)   (de-aliased from Qg -> rides prep; 4-kernel graph, R11-verified)
// blocks [768,2304): Wqkv[3072][1024] = bf16(wq|wk|wv)
// blocks [2304,4352): xb = bf16(x)
__global__ void prep_kernel(const float* __restrict__ x,
                            const float* __restrict__ wq, const float* __restrict__ wk,
                            const float* __restrict__ wv, const float* __restrict__ wo,
                            ushort_t* __restrict__ Wqkv, ushort_t* __restrict__ xb,
                            ushort_t* __restrict__ Wob,
                            float* __restrict__ cos_t, float* __restrict__ sin_t) {
    const int b = blockIdx.x;
    if (b < 256) {
        int tid = b * 256 + threadIdx.x;           // 0..65535
        int i = tid & 31, pos = tid >> 5;
        float freq = expf(-9.210340372f * (float)(2 * i) / 64.0f);
        float ang = (float)pos * freq;
        cos_t[tid] = cosf(ang);
        sin_t[tid] = sinf(ang);
    } else if (b < 768) {
        int tid = (b - 256) * 256 + threadIdx.x;   // 0..131071
        int off = tid * 8;
        f32x4 a = ((const f32x4*)(wo + off))[0];
        f32x4 c = ((const f32x4*)(wo + off))[1];
        *(bf16x8*)&Wob[off] = cvt8(a, c);
    } else if (b < 2304) {
        int tid = (b - 768) * 256 + threadIdx.x;   // 0..393215
        int z = tid >> 17;
        int off = (tid & 131071) * 8;
        const float* src = (z == 0) ? wq : (z == 1) ? wk : wv;
        f32x4 a = ((const f32x4*)(src + off))[0];
        f32x4 c = ((const f32x4*)(src + off))[1];
        *(bf16x8*)&Wqkv[(size_t)z * 1048576 + off] = cvt8(a, c);
    } else {
        int tid = (b - 2304) * 256 + threadIdx.x;  // 0..524287
        int off = tid * 8;
        f32x4 a = ((const f32x4*)(x + off))[0];
        f32x4 c = ((const f32x4*)(x + off))[1];
        *(bf16x8*)&xb[off] = cvt8(a, c);
    }
}

// ---------------- Fused QKV projection + RoPE + V-transpose ----------------
// A/B: REVERTED to the thrice-measured 60-us 128x64 version (R8/R9/R13-verified);
// everything else byte-identical to R15. R15's proj-256^2 was 75.4 us in isolation
// (1 block/CU drain, 75% CU coverage) yet total improved 203->193 — this round
// disambiguates whether the non-proj 24-us swing was coupled to the proj change.
// C = Xb * Wqkv^T, both bf16. Tile 128(M) x 64(N), BK=32, wave tile 64x32.
// Triple-buffered gload LDS with counted vmcnt; grid (48, 32) = 1536 blocks.
// Q pre-scaled by 1/8.
__global__ __launch_bounds__(256) void proj_qkv_kernel(
    const ushort_t* __restrict__ xb, const ushort_t* __restrict__ Wqkv,
    const float* __restrict__ cos_t, const float* __restrict__ sin_t,
    const int* __restrict__ tokpos,
    ushort_t* __restrict__ Qg, ushort_t* __restrict__ Kg, ushort_t* __restrict__ Vt)
{
    __shared__ __align__(16) short lA[3][128 * 32];   // 3 x 8 KB
    __shared__ __align__(16) short lB[3][64 * 32];    // 3 x 4 KB

    const int t = threadIdx.x;
    const int lane = t & 63;
    const int wid = t >> 6;
    const int quad = lane >> 4, l16 = lane & 15;
    const int mh = wid >> 1, nh = wid & 1;   // wave: 64(M) x 32(N)
    const int Mb = blockIdx.y * 128;
    const int NbG = blockIdx.x * 64;
    const int z = NbG >> 10;
    const int Nb = NbG & 1023;

    f32x4 acc[4][2] = {};

    auto stage = [&](int buf, int k0) {
        #pragma unroll
        for (int i = 0; i < 2; ++i) {   // A: 32 rows per wave
            int rbase = wid * 32 + i * 16;
            int row = rbase + (lane >> 2);
            int gch = (lane & 3) ^ ((lane >> 3) & 3);
            gload_lds16(xb + (size_t)(Mb + row) * DM + k0 + gch * 8, &lA[buf][rbase * 32]);
        }
        {   // B: 16 rows per wave
            int rbase = wid * 16;
            int row = rbase + (lane >> 2);
            int gch = (lane & 3) ^ ((lane >> 3) & 3);
            gload_lds16(Wqkv + (size_t)(NbG + row) * DM + k0 + gch * 8, &lB[buf][rbase * 32]);
        }
    };

    stage(0, 0);
    stage(1, 32);

    for (int kt = 0; kt < 32; ++kt) {
        const int cur = kt % 3;
        if (kt == 31) asm volatile("s_waitcnt vmcnt(0)" ::: "memory");
        else          asm volatile("s_waitcnt vmcnt(3)" ::: "memory");
        __builtin_amdgcn_s_barrier();
        if (kt < 30) stage((kt + 2) % 3, kt * 32 + 64);

        bf16x8 a[4], b[2];
        #pragma unroll
        for (int mt = 0; mt < 4; ++mt) {
            int row = mh * 64 + mt * 16 + l16;
            int slot = quad ^ ((l16 >> 1) & 3);
            a[mt] = *(const bf16x8*)&lA[cur][row * 32 + slot * 8];
        }
        #pragma unroll
        for (int nt = 0; nt < 2; ++nt) {
            int row = nh * 32 + nt * 16 + l16;
            int slot = quad ^ ((l16 >> 1) & 3);
            b[nt] = *(const bf16x8*)&lB[cur][row * 32 + slot * 8];
        }
        __builtin_amdgcn_s_setprio(1);
        #pragma unroll
        for (int mt = 0; mt < 4; ++mt)
            #pragma unroll
            for (int nt = 0; nt < 2; ++nt)
                acc[mt][nt] = __builtin_amdgcn_mfma_f32_16x16x32_bf16(a[mt], b[nt], acc[mt][nt], 0, 0, 0);
        __builtin_amdgcn_s_setprio(0);
    }

    const int bb = Mb >> 11;
    if (z == 2) {
        #pragma unroll
        for (int mt = 0; mt < 4; ++mt) {
            const int s0 = (Mb + mh * 64 + mt * 16 + quad * 4) & (SEQ - 1);
            #pragma unroll
            for (int nt = 0; nt < 2; ++nt) {
                int col = Nb + nh * 32 + nt * 16 + l16;
                int h = col >> 6, d = col & 63;
                s16x4 pk;
                #pragma unroll
                for (int r = 0; r < 4; ++r) pk[r] = f2bf(acc[mt][nt][r]);
                *(s16x4*)&Vt[((size_t)(bb * NH + h) * DKV + d) * SEQ + s0] = pk;
            }
        }
    } else {
        ushort_t* dst = (z == 0) ? Qg : Kg;
        const float qscale = (z == 0) ? 0.125f : 1.0f;
        #pragma unroll
        for (int mt = 0; mt < 4; ++mt) {
            #pragma unroll
            for (int nt = 0; nt < 2; ++nt) {
                #pragma unroll
                for (int r = 0; r < 4; ++r) {
                    int row = Mb + mh * 64 + mt * 16 + quad * 4 + r;
                    int s = row & (SEQ - 1);
                    int col = Nb + nh * 32 + nt * 16 + l16;
                    int h = col >> 6, d = col & 63;
                    float val = acc[mt][nt][r];
                    float part = __shfl_xor(val, 1, 64);
                    int pos = tokpos[s];
                    int i = d >> 1;
                    float c = cos_t[pos * 32 + i];
                    float sn = sin_t[pos * 32 + i];
                    val = (d & 1) ? (val * c + part * sn) : (val * c - part * sn);
                    val *= qscale;
                    dst[((size_t)(bb * NH + h) * SEQ + s) * DKV + d] = (ushort_t)f2bf(val);
                }
            }
        }
    }
}

// ---------------- Causal flash attention: folded triangle, 128-k staging / 64-k compute ----------------
// R13 form (best-measured). Block handles q-tile pair (qt, 31-qt): 17 staged
// 128-tiles per pair, perfect balance. Per-wave half-skip drops fully-masked
// halves. LDS 73 KB -> 2 blocks/CU, 8 waves/CU.
__global__ __launch_bounds__(256, 2) void attn_kernel(
    const ushort_t* __restrict__ Q, const ushort_t* __restrict__ K,
    const ushort_t* __restrict__ Vt, ushort_t* __restrict__ O)
{
    __shared__ __align__(16) short lK[2][2][64 * 64];   // [buf][half] 32 KB
    __shared__ __align__(16) short lV[2][2][64 * 64];   // [buf][half] 32 KB (V^T: [d][k])
    __shared__ __align__(16) short lP[4][16 * PST2];    // 9 KB, wave-private quarters

    const int t = threadIdx.x;
    const int lane = t & 63;
    const int wid = t >> 6;                     // 0..3
    const int quad = lane >> 4, l16 = lane & 15;
    const int bh = blockIdx.y;
    const int bb = bh >> 4, h = bh & 15;

    const ushort_t* Qb = Q + (size_t)bh * SEQ * DKV;
    const ushort_t* Kb = K + (size_t)bh * SEQ * DKV;
    const ushort_t* Vtb = Vt + (size_t)bh * DKV * SEQ;
    short* myP = lP[wid];

    auto stage = [&](int kb, int buf) {
        #pragma unroll
        for (int hf = 0; hf < 2; ++hf) {
            #pragma unroll
            for (int j = 0; j < 2; ++j) {       // K half: 16 rows/wave, 8 rows/instr
                int rbase = wid * 16 + j * 8;
                int row = rbase + (lane >> 3);
                int gch = (lane & 7) ^ (row & 7);
                gload_lds16(Kb + (size_t)(kb + hf * 64 + row) * DKV + gch * 8,
                            &lK[buf][hf][rbase * 64]);
            }
            #pragma unroll
            for (int j = 0; j < 2; ++j) {       // V^T half: rows are d, 64 k-cols
                int rbase = wid * 16 + j * 8;
                int row = rbase + (lane >> 3);
                int gch = (lane & 7) ^ (row & 7);
                gload_lds16(Vtb + (size_t)row * SEQ + kb + hf * 64 + gch * 8,
                            &lV[buf][hf][rbase * 64]);
            }
        }
    };

    #pragma unroll 1
    for (int ph = 0; ph < 2; ++ph) {
        const int qt = ph ? (31 - (int)blockIdx.x) : (int)blockIdx.x;
        const int q0w = qt * 64 + wid * 16;
        const int nkt2 = (qt >> 1) + 1;         // 128-wide staged tiles

        bf16x8 bq[2];
        #pragma unroll
        for (int hq = 0; hq < 2; ++hq)
            bq[hq] = *(const bf16x8*)(Qb + (size_t)(q0w + l16) * DKV + hq * 32 + quad * 8);

        f32x4 acc[4] = {};
        float ps = 0.f;

        if (ph) __syncthreads();
        stage(0, 0);

        for (int kt2 = 0; kt2 < nkt2; ++kt2) {
            const int kb128 = kt2 * 128;
            __syncthreads();                    // drains stage(kt2)
            if (kt2 + 1 < nkt2) stage(kb128 + 128, (kt2 + 1) & 1);

            #pragma unroll
            for (int hf = 0; hf < 2; ++hf) {
                const int kbase = kb128 + hf * 64;
                if (kbase > q0w + 15) continue; // half fully beyond this wave's rows

                const short* bK = lK[kt2 & 1][hf];
                const short* bV = lV[kt2 & 1][hf];

                bf16x8 ak[4][2];
                #pragma unroll
                for (int mt = 0; mt < 4; ++mt)
                    #pragma unroll
                    for (int hh = 0; hh < 2; ++hh) {
                        int row = mt * 16 + l16;
                        int slot = (hh * 4 + quad) ^ (row & 7);
                        ak[mt][hh] = *(const bf16x8*)&bK[row * 64 + slot * 8];
                    }

                f32x4 st[4];
                __builtin_amdgcn_s_setprio(1);
                #pragma unroll
                for (int mt = 0; mt < 4; ++mt) {
                    f32x4 zz = {};
                    zz = __builtin_amdgcn_mfma_f32_16x16x32_bf16(ak[mt][0], bq[0], zz, 0, 0, 0);
                    zz = __builtin_amdgcn_mfma_f32_16x16x32_bf16(ak[mt][1], bq[1], zz, 0, 0, 0);
                    st[mt] = zz;
                }
                __builtin_amdgcn_s_setprio(0);

                if (kbase + 63 > q0w) {
                    #pragma unroll
                    for (int mt = 0; mt < 4; ++mt) {
                        float pv[4];
                        #pragma unroll
                        for (int r = 0; r < 4; ++r) {
                            int k_abs = kbase + mt * 16 + quad * 4 + r;
                            int q_abs = q0w + l16;
                            pv[r] = (k_abs > q_abs) ? 0.f : __expf(st[mt][r]);
                            ps += pv[r];
                        }
                        *(s16x4*)&myP[l16 * PST2 + mt * 16 + quad * 4] = cvt4(pv[0], pv[1], pv[2], pv[3]);
                    }
                } else {
                    #pragma unroll
                    for (int mt = 0; mt < 4; ++mt) {
                        float pv[4];
                        #pragma unroll
                        for (int r = 0; r < 4; ++r) {
                            pv[r] = __expf(st[mt][r]);
                            ps += pv[r];
                        }
                        *(s16x4*)&myP[l16 * PST2 + mt * 16 + quad * 4] = cvt4(pv[0], pv[1], pv[2], pv[3]);
                    }
                }

                bf16x8 ap[2];
                ap[0] = *(const bf16x8*)&myP[l16 * PST2 + quad * 8];
                ap[1] = *(const bf16x8*)&myP[l16 * PST2 + 32 + quad * 8];

                __builtin_amdgcn_s_setprio(1);
                #pragma unroll
                for (int d = 0; d < 4; ++d) {
                    int row = d * 16 + l16;
                    int slot0 = quad ^ (row & 7);
                    int slot1 = (4 + quad) ^ (row & 7);
                    bf16x8 bv0 = *(const bf16x8*)&bV[row * 64 + slot0 * 8];
                    bf16x8 bv1 = *(const bf16x8*)&bV[row * 64 + slot1 * 8];
                    acc[d] = __builtin_amdgcn_mfma_f32_16x16x32_bf16(ap[0], bv0, acc[d], 0, 0, 0);
                    acc[d] = __builtin_amdgcn_mfma_f32_16x16x32_bf16(ap[1], bv1, acc[d], 0, 0, 0);
                }
                __builtin_amdgcn_s_setprio(0);
            }
        }

        // epilogue (per wave)
        ps += __shfl_xor(ps, 16, 64);
        ps += __shfl_xor(ps, 32, 64);
        float* lLw = (float*)myP;   // P dead, reuse (wave-private)
        if (quad == 0) lLw[l16] = ps;
        f32x4 lv = *(const f32x4*)&lLw[quad * 4];
        f32x4 inv;
        #pragma unroll
        for (int r = 0; r < 4; ++r) inv[r] = 1.0f / lv[r];
        #pragma unroll
        for (int d = 0; d < 4; ++d)
            #pragma unroll
            for (int r = 0; r < 4; ++r) {
                int qrow = q0w + quad * 4 + r;
                int dd = d * 16 + l16;
                O[(size_t)(bb * SEQ + qrow) * DM + h * DKV + dd] = (ushort_t)f2bf(acc[d][r] * inv[r]);
            }
    }
}

// ---------------- Output projection: out = AO * Wob^T (all bf16) ----------------
// proj skeleton (R9-verified): tile 128(M) x 64(N), BK=32, wave tile 64x32,
// triple-buffered gload LDS + counted vmcnt. grid (16, 32) = 512 blocks = 2/CU.
__global__ __launch_bounds__(256) void oproj_kernel(
    const ushort_t* __restrict__ A, const ushort_t* __restrict__ B, float* __restrict__ out)
{
    __shared__ __align__(16) short lA[3][128 * 32];   // 3 x 8 KB
    __shared__ __align__(16) short lB[3][64 * 32];    // 3 x 4 KB

    const int t = threadIdx.x;
    const int lane = t & 63;
    const int wid = t >> 6;
    const int quad = lane >> 4, l16 = lane & 15;
    const int mh = wid >> 1, nh = wid & 1;   // wave: 64(M) x 32(N)
    const int Mb = blockIdx.y * 128;
    const int Nb = blockIdx.x * 64;

    f32x4 acc[4][2] = {};

    auto stage = [&](int buf, int k0) {
        #pragma unroll
        for (int i = 0; i < 2; ++i) {   // A: 32 rows per wave
            int rbase = wid * 32 + i * 16;
            int row = rbase + (lane >> 2);
            int gch = (lane & 3) ^ ((lane >> 3) & 3);
            gload_lds16(A + (size_t)(Mb + row) * DM + k0 + gch * 8, &lA[buf][rbase * 32]);
        }
        {   // B: 16 rows per wave
            int rbase = wid * 16;
            int row = rbase + (lane >> 2);
            int gch = (lane & 3) ^ ((lane >> 3) & 3);
            gload_lds16(B + (size_t)(Nb + row) * DM + k0 + gch * 8, &lB[buf][rbase * 32]);
        }
    };

    stage(0, 0);
    stage(1, 32);

    for (int kt = 0; kt < 32; ++kt) {
        const int cur = kt % 3;
        if (kt == 31) asm volatile("s_waitcnt vmcnt(0)" ::: "memory");
        else          asm volatile("s_waitcnt vmcnt(3)" ::: "memory");
        __builtin_amdgcn_s_barrier();
        if (kt < 30) stage((kt + 2) % 3, kt * 32 + 64);

        bf16x8 a[4], b[2];
        #pragma unroll
        for (int mt = 0; mt < 4; ++mt) {
            int row = mh * 64 + mt * 16 + l16;
            int slot = quad ^ ((l16 >> 1) & 3);
            a[mt] = *(const bf16x8*)&lA[cur][row * 32 + slot * 8];
        }
        #pragma unroll
        for (int nt = 0; nt < 2; ++nt) {
            int row = nh * 32 + nt * 16 + l16;
            int slot = quad ^ ((l16 >> 1) & 3);
            b[nt] = *(const bf16x8*)&lB[cur][row * 32 + slot * 8];
        }
        __builtin_amdgcn_s_setprio(1);
        #pragma unroll
        for (int mt = 0; mt < 4; ++mt)
            #pragma unroll
            for (int nt = 0; nt < 2; ++nt)
                acc[mt][nt] = __builtin_amdgcn_mfma_f32_16x16x32_bf16(a[mt], b[nt], acc[mt][nt], 0, 0, 0);
        __builtin_amdgcn_s_setprio(0);
    }

    #pragma unroll
    for (int mt = 0; mt < 4; ++mt)
        #pragma unroll
        for (int nt = 0; nt < 2; ++nt)
            #pragma unroll
            for (int r = 0; r < 4; ++r) {
                int row = Mb + mh * 64 + mt * 16 + quad * 4 + r;
                int col = Nb + nh * 32 + nt * 16 + l16;
                out[(size_t)row * DM + col] = acc[mt][nt][r];
            }
}

extern "C" void kernel_launch(void* const* d_in, const int* in_sizes, int n_in,
                              void* d_out, int out_size, void* d_ws, size_t ws_size,
                              hipStream_t stream) {
    const float* x  = (const float*)d_in[0];
    const float* wq = (const float*)d_in[1];
    const float* wk = (const float*)d_in[2];
    const float* wv = (const float*)d_in[3];
    const float* wo = (const float*)d_in[4];
    const int* tokpos = (const int*)d_in[5];
    float* out = (float*)d_out;

    // Memory map (4-kernel graph; Wob de-aliased from Qg so wo-convert rides prep):
    //  ws[0:8M)    cos/sin + Wqkv (live prep->proj) -> AO (written by attn)
    //  ws[8:16M)   Qg (live through attn)
    //  ws[16:24M)  Kg (live through attn)
    //  ws[24:26M)  Wob (written by prep, read by oproj — untouched in between)
    //  d_out[0:8M)  xb (dead after proj; oproj overwrites with out)
    //  d_out[8:16M) Vt (dead after attn; oproj overwrites with out — oproj is last)
    char* ws = (char*)d_ws;
    float* cos_t    = (float*)ws;                          // 256 KB
    float* sin_t    = (float*)(ws + 256 * 1024);           // 256 KB
    ushort_t* Wqkv  = (ushort_t*)(ws + 512 * 1024);        // 6 MB
    ushort_t* AO    = (ushort_t*)ws;                       // 8 MB (aliases the above)
    ushort_t* Qg    = (ushort_t*)(ws + (size_t)8  * 1024 * 1024);  // 8 MB
    ushort_t* Kg    = (ushort_t*)(ws + (size_t)16 * 1024 * 1024);  // 8 MB
    ushort_t* Wob   = (ushort_t*)(ws + (size_t)24 * 1024 * 1024);  // 2 MB
    ushort_t* xb    = (ushort_t*)d_out;                            // 8 MB scratch
    ushort_t* Vt    = (ushort_t*)((char*)d_out + (size_t)8 * 1024 * 1024);  // 8 MB scratch

    prep_kernel<<<4352, 256, 0, stream>>>(x, wq, wk, wv, wo, Wqkv, xb, Wob, cos_t, sin_t);
    proj_qkv_kernel<<<dim3(3 * DM / 64, MTOT / 128), 256, 0, stream>>>(
        xb, Wqkv, cos_t, sin_t, tokpos, Qg, Kg, Vt);
    attn_kernel<<<dim3(SEQ / 128, 32), 256, 0, stream>>>(Qg, Kg, Vt, AO);
    oproj_kernel<<<dim3(DM / 64, MTOT / 128), 256, 0, stream>>>(AO, Wob, out);
}

// Round 17
// 198.084 us; speedup vs baseline: 1.0273x; 1.0273x over previous
//
#include <hip/hip_runtime.h>
#include <hip/hip_bf16.h>
#include <math.h>

#define SEQ 2048
#define DM 1024
#define NH 16
#define DKV 64
#define MTOT 4096   /* BATCH*SEQ */
#define PST2 72     /* P-tile LDS row stride in shorts (64 + 8 pad) */

typedef __attribute__((ext_vector_type(8))) short bf16x8;
typedef __attribute__((ext_vector_type(4))) short s16x4;
typedef __attribute__((ext_vector_type(4))) float f32x4;
typedef unsigned short ushort_t;

__device__ __forceinline__ short f2bf(float f) {
    union { float f; unsigned u; } v; v.f = f;
    unsigned r = v.u + 0x7fffu + ((v.u >> 16) & 1u);
    return (short)(r >> 16);
}

__device__ __forceinline__ bf16x8 cvt8(f32x4 a, f32x4 b) {
    union { __hip_bfloat162 h[4]; bf16x8 v; } u;
    u.h[0] = __float22bfloat162_rn(float2{a[0], a[1]});
    u.h[1] = __float22bfloat162_rn(float2{a[2], a[3]});
    u.h[2] = __float22bfloat162_rn(float2{b[0], b[1]});
    u.h[3] = __float22bfloat162_rn(float2{b[2], b[3]});
    return u.v;
}

__device__ __forceinline__ s16x4 cvt4(float a, float b, float c, float d) {
    union { __hip_bfloat162 h[2]; s16x4 v; } u;
    u.h[0] = __float22bfloat162_rn(float2{a, b});
    u.h[1] = __float22bfloat162_rn(float2{c, d});
    return u.v;
}

// async global->LDS, 16B per lane. LDS dest = wave-uniform base + lane*16.
__device__ __forceinline__ void gload_lds16(const void* g, void* l) {
    __builtin_amdgcn_global_load_lds(
        (const __attribute__((address_space(1))) unsigned int*)g,
        (__attribute__((address_space(3))) unsigned int*)l, 16, 0, 0);
}

// ---------------- fused prep: RoPE tables + wo + Wqkv fuse + x convert, one launch ----------------
// blocks [0,256): cos/sin tables (fp32)
// blocks [256,768): Wob = bf16(wo)   (de-aliased from Qg -> rides prep; 4-kernel graph, R11-verified)
// blocks [768,2304): Wqkv[3072][1024] = bf16(wq|wk|wv)
// blocks [2304,4352): xb = bf16(x)
__global__ void prep_kernel(const float* __restrict__ x,
                            const float* __restrict__ wq, const float* __restrict__ wk,
                            const float* __restrict__ wv, const float* __restrict__ wo,
                            ushort_t* __restrict__ Wqkv, ushort_t* __restrict__ xb,
                            ushort_t* __restrict__ Wob,
                            float* __restrict__ cos_t, float* __restrict__ sin_t) {
    const int b = blockIdx.x;
    if (b < 256) {
        int tid = b * 256 + threadIdx.x;           // 0..65535
        int i = tid & 31, pos = tid >> 5;
        float freq = expf(-9.210340372f * (float)(2 * i) / 64.0f);
        float ang = (float)pos * freq;
        cos_t[tid] = cosf(ang);
        sin_t[tid] = sinf(ang);
    } else if (b < 768) {
        int tid = (b - 256) * 256 + threadIdx.x;   // 0..131071
        int off = tid * 8;
        f32x4 a = ((const f32x4*)(wo + off))[0];
        f32x4 c = ((const f32x4*)(wo + off))[1];
        *(bf16x8*)&Wob[off] = cvt8(a, c);
    } else if (b < 2304) {
        int tid = (b - 768) * 256 + threadIdx.x;   // 0..393215
        int z = tid >> 17;
        int off = (tid & 131071) * 8;
        const float* src = (z == 0) ? wq : (z == 1) ? wk : wv;
        f32x4 a = ((const f32x4*)(src + off))[0];
        f32x4 c = ((const f32x4*)(src + off))[1];
        *(bf16x8*)&Wqkv[(size_t)z * 1048576 + off] = cvt8(a, c);
    } else {
        int tid = (b - 2304) * 256 + threadIdx.x;  // 0..524287
        int off = tid * 8;
        f32x4 a = ((const f32x4*)(x + off))[0];
        f32x4 c = ((const f32x4*)(x + off))[1];
        *(bf16x8*)&xb[off] = cvt8(a, c);
    }
}

// ---------------- Fused QKV projection + RoPE + V-transpose: 256x256 tile + counted vmcnt ----------------
// R15/R16 A/B proved the 256^2 shell is globally optimal (total 193.3 vs 203.5)
// even though its vmcnt(0) drain at 1 block/CU is its own worst defect (75.4 us,
// MfmaUtil 12.5%). Fix: BK 64->32 so the proven R4/R9 counted-vmcnt TRIPLE buffer
// fits (3 x 32 KB = 96 KB LDS): 4 loads/wave/stage -> vmcnt(4), prefetch depth 2,
// drain only on the last iter. Counted vmcnt was null at 2-6 blocks/CU (TLP cover)
// but at 1/CU nothing else covers the latency. All coupling-relevant geometry
// preserved: 256^2 tile, 192-block grid, 512 thr, 1 block/CU, same epilogue.
// 32 MFMA / 12 ds_read per iter. Q pre-scaled by 1/8.
__global__ __launch_bounds__(512) void proj_qkv_kernel(
    const ushort_t* __restrict__ xb, const ushort_t* __restrict__ Wqkv,
    const float* __restrict__ cos_t, const float* __restrict__ sin_t,
    const int* __restrict__ tokpos,
    ushort_t* __restrict__ Qg, ushort_t* __restrict__ Kg, ushort_t* __restrict__ Vt)
{
    __shared__ __align__(16) short lA[3][256 * 32];   // 3 x 16 KB
    __shared__ __align__(16) short lB[3][256 * 32];   // 3 x 16 KB

    const int t = threadIdx.x;
    const int lane = t & 63;
    const int wid = t >> 6;                  // 0..7
    const int quad = lane >> 4, l16 = lane & 15;
    const int wm = wid >> 2, wn = wid & 3;   // wave tile 128(M) x 64(N)
    const int Mb = blockIdx.y * 256;
    const int NbG = blockIdx.x * 256;
    const int z = NbG >> 10;
    const int Nb = NbG & 1023;

    f32x4 acc[8][4] = {};

    // Stage one BK=32 tile: per wave 32 rows of A and 32 rows of B, 2 instrs of
    // 16 rows each (64 lanes x 16B; lane>>2 = row, lane&3 = chunk). Swizzle is the
    // byte-proven 128x64-proj pair: write gch=(lane&3)^((lane>>3)&3), read
    // slot=quad^((l16>>1)&3).
    auto stage = [&](int buf, int k0) {
        #pragma unroll
        for (int i = 0; i < 2; ++i) {
            int rbase = wid * 32 + i * 16;
            int row = rbase + (lane >> 2);
            int gch = (lane & 3) ^ ((lane >> 3) & 3);
            gload_lds16(xb + (size_t)(Mb + row) * DM + k0 + gch * 8, &lA[buf][rbase * 32]);
        }
        #pragma unroll
        for (int i = 0; i < 2; ++i) {
            int rbase = wid * 32 + i * 16;
            int row = rbase + (lane >> 2);
            int gch = (lane & 3) ^ ((lane >> 3) & 3);
            gload_lds16(Wqkv + (size_t)(NbG + row) * DM + k0 + gch * 8, &lB[buf][rbase * 32]);
        }
    };

    stage(0, 0);
    stage(1, 32);

    for (int kt = 0; kt < 32; ++kt) {
        const int cur = kt % 3;
        // own outstanding: stage(kt) [+ stage(kt+1)]. vmcnt(4) leaves kt+1's 4
        // loads in flight across the barrier; only the last iter drains fully.
        if (kt == 31) asm volatile("s_waitcnt vmcnt(0)" ::: "memory");
        else          asm volatile("s_waitcnt vmcnt(4)" ::: "memory");
        __builtin_amdgcn_s_barrier();
        if (kt < 30) stage((kt + 2) % 3, kt * 32 + 64);

        bf16x8 a[8], b[4];
        #pragma unroll
        for (int mf = 0; mf < 8; ++mf) {
            int row = wm * 128 + mf * 16 + l16;
            int slot = quad ^ ((l16 >> 1) & 3);
            a[mf] = *(const bf16x8*)&lA[cur][row * 32 + slot * 8];
        }
        #pragma unroll
        for (int nf = 0; nf < 4; ++nf) {
            int row = wn * 64 + nf * 16 + l16;
            int slot = quad ^ ((l16 >> 1) & 3);
            b[nf] = *(const bf16x8*)&lB[cur][row * 32 + slot * 8];
        }
        __builtin_amdgcn_s_setprio(1);
        #pragma unroll
        for (int mf = 0; mf < 8; ++mf)
            #pragma unroll
            for (int nf = 0; nf < 4; ++nf)
                acc[mf][nf] = __builtin_amdgcn_mfma_f32_16x16x32_bf16(a[mf], b[nf], acc[mf][nf], 0, 0, 0);
        __builtin_amdgcn_s_setprio(0);
    }

    // Epilogue: identical to the R15-verified 256^2 version. 256-tiles never
    // straddle z-slices (256|1024) or batch boundaries (256|2048).
    const int bb = Mb >> 11;
    if (z == 2) {
        #pragma unroll
        for (int mf = 0; mf < 8; ++mf) {
            const int s0 = (Mb + wm * 128 + mf * 16 + quad * 4) & (SEQ - 1);
            #pragma unroll
            for (int nf = 0; nf < 4; ++nf) {
                int col = Nb + wn * 64 + nf * 16 + l16;
                int h = col >> 6, d = col & 63;
                s16x4 pk;
                #pragma unroll
                for (int r = 0; r < 4; ++r) pk[r] = f2bf(acc[mf][nf][r]);
                *(s16x4*)&Vt[((size_t)(bb * NH + h) * DKV + d) * SEQ + s0] = pk;
            }
        }
    } else {
        ushort_t* dst = (z == 0) ? Qg : Kg;
        const float qscale = (z == 0) ? 0.125f : 1.0f;
        #pragma unroll
        for (int mf = 0; mf < 8; ++mf) {
            #pragma unroll
            for (int nf = 0; nf < 4; ++nf) {
                #pragma unroll
                for (int r = 0; r < 4; ++r) {
                    int row = Mb + wm * 128 + mf * 16 + quad * 4 + r;
                    int s = row & (SEQ - 1);
                    int col = Nb + wn * 64 + nf * 16 + l16;
                    int h = col >> 6, d = col & 63;
                    float val = acc[mf][nf][r];
                    float part = __shfl_xor(val, 1, 64);
                    int pos = tokpos[s];
                    int i = d >> 1;
                    float c = cos_t[pos * 32 + i];
                    float sn = sin_t[pos * 32 + i];
                    val = (d & 1) ? (val * c + part * sn) : (val * c - part * sn);
                    val *= qscale;
                    dst[((size_t)(bb * NH + h) * SEQ + s) * DKV + d] = (ushort_t)f2bf(val);
                }
            }
        }
    }
}

// ---------------- Causal flash attention: folded triangle, 128-k staging / 64-k compute ----------------
// R13 form (best-measured). Block handles q-tile pair (qt, 31-qt): 17 staged
// 128-tiles per pair, perfect balance. Per-wave half-skip drops fully-masked
// halves. LDS 73 KB -> 2 blocks/CU, 8 waves/CU.
__global__ __launch_bounds__(256, 2) void attn_kernel(
    const ushort_t* __restrict__ Q, const ushort_t* __restrict__ K,
    const ushort_t* __restrict__ Vt, ushort_t* __restrict__ O)
{
    __shared__ __align__(16) short lK[2][2][64 * 64];   // [buf][half] 32 KB
    __shared__ __align__(16) short lV[2][2][64 * 64];   // [buf][half] 32 KB (V^T: [d][k])
    __shared__ __align__(16) short lP[4][16 * PST2];    // 9 KB, wave-private quarters

    const int t = threadIdx.x;
    const int lane = t & 63;
    const int wid = t >> 6;                     // 0..3
    const int quad = lane >> 4, l16 = lane & 15;
    const int bh = blockIdx.y;
    const int bb = bh >> 4, h = bh & 15;

    const ushort_t* Qb = Q + (size_t)bh * SEQ * DKV;
    const ushort_t* Kb = K + (size_t)bh * SEQ * DKV;
    const ushort_t* Vtb = Vt + (size_t)bh * DKV * SEQ;
    short* myP = lP[wid];

    auto stage = [&](int kb, int buf) {
        #pragma unroll
        for (int hf = 0; hf < 2; ++hf) {
            #pragma unroll
            for (int j = 0; j < 2; ++j) {       // K half: 16 rows/wave, 8 rows/instr
                int rbase = wid * 16 + j * 8;
                int row = rbase + (lane >> 3);
                int gch = (lane & 7) ^ (row & 7);
                gload_lds16(Kb + (size_t)(kb + hf * 64 + row) * DKV + gch * 8,
                            &lK[buf][hf][rbase * 64]);
            }
            #pragma unroll
            for (int j = 0; j < 2; ++j) {       // V^T half: rows are d, 64 k-cols
                int rbase = wid * 16 + j * 8;
                int row = rbase + (lane >> 3);
                int gch = (lane & 7) ^ (row & 7);
                gload_lds16(Vtb + (size_t)row * SEQ + kb + hf * 64 + gch * 8,
                            &lV[buf][hf][rbase * 64]);
            }
        }
    };

    #pragma unroll 1
    for (int ph = 0; ph < 2; ++ph) {
        const int qt = ph ? (31 - (int)blockIdx.x) : (int)blockIdx.x;
        const int q0w = qt * 64 + wid * 16;
        const int nkt2 = (qt >> 1) + 1;         // 128-wide staged tiles

        bf16x8 bq[2];
        #pragma unroll
        for (int hq = 0; hq < 2; ++hq)
            bq[hq] = *(const bf16x8*)(Qb + (size_t)(q0w + l16) * DKV + hq * 32 + quad * 8);

        f32x4 acc[4] = {};
        float ps = 0.f;

        if (ph) __syncthreads();
        stage(0, 0);

        for (int kt2 = 0; kt2 < nkt2; ++kt2) {
            const int kb128 = kt2 * 128;
            __syncthreads();                    // drains stage(kt2)
            if (kt2 + 1 < nkt2) stage(kb128 + 128, (kt2 + 1) & 1);

            #pragma unroll
            for (int hf = 0; hf < 2; ++hf) {
                const int kbase = kb128 + hf * 64;
                if (kbase > q0w + 15) continue; // half fully beyond this wave's rows

                const short* bK = lK[kt2 & 1][hf];
                const short* bV = lV[kt2 & 1][hf];

                bf16x8 ak[4][2];
                #pragma unroll
                for (int mt = 0; mt < 4; ++mt)
                    #pragma unroll
                    for (int hh = 0; hh < 2; ++hh) {
                        int row = mt * 16 + l16;
                        int slot = (hh * 4 + quad) ^ (row & 7);
                        ak[mt][hh] = *(const bf16x8*)&bK[row * 64 + slot * 8];
                    }

                f32x4 st[4];
                __builtin_amdgcn_s_setprio(1);
                #pragma unroll
                for (int mt = 0; mt < 4; ++mt) {
                    f32x4 zz = {};
                    zz = __builtin_amdgcn_mfma_f32_16x16x32_bf16(ak[mt][0], bq[0], zz, 0, 0, 0);
                    zz = __builtin_amdgcn_mfma_f32_16x16x32_bf16(ak[mt][1], bq[1], zz, 0, 0, 0);
                    st[mt] = zz;
                }
                __builtin_amdgcn_s_setprio(0);

                if (kbase + 63 > q0w) {
                    #pragma unroll
                    for (int mt = 0; mt < 4; ++mt) {
                        float pv[4];
                        #pragma unroll
                        for (int r = 0; r < 4; ++r) {
                            int k_abs = kbase + mt * 16 + quad * 4 + r;
                            int q_abs = q0w + l16;
                            pv[r] = (k_abs > q_abs) ? 0.f : __expf(st[mt][r]);
                            ps += pv[r];
                        }
                        *(s16x4*)&myP[l16 * PST2 + mt * 16 + quad * 4] = cvt4(pv[0], pv[1], pv[2], pv[3]);
                    }
                } else {
                    #pragma unroll
                    for (int mt = 0; mt < 4; ++mt) {
                        float pv[4];
                        #pragma unroll
                        for (int r = 0; r < 4; ++r) {
                            pv[r] = __expf(st[mt][r]);
                            ps += pv[r];
                        }
                        *(s16x4*)&myP[l16 * PST2 + mt * 16 + quad * 4] = cvt4(pv[0], pv[1], pv[2], pv[3]);
                    }
                }

                bf16x8 ap[2];
                ap[0] = *(const bf16x8*)&myP[l16 * PST2 + quad * 8];
                ap[1] = *(const bf16x8*)&myP[l16 * PST2 + 32 + quad * 8];

                __builtin_amdgcn_s_setprio(1);
                #pragma unroll
                for (int d = 0; d < 4; ++d) {
                    int row = d * 16 + l16;
                    int slot0 = quad ^ (row & 7);
                    int slot1 = (4 + quad) ^ (row & 7);
                    bf16x8 bv0 = *(const bf16x8*)&bV[row * 64 + slot0 * 8];
                    bf16x8 bv1 = *(const bf16x8*)&bV[row * 64 + slot1 * 8];
                    acc[d] = __builtin_amdgcn_mfma_f32_16x16x32_bf16(ap[0], bv0, acc[d], 0, 0, 0);
                    acc[d] = __builtin_amdgcn_mfma_f32_16x16x32_bf16(ap[1], bv1, acc[d], 0, 0, 0);
                }
                __builtin_amdgcn_s_setprio(0);
            }
        }

        // epilogue (per wave)
        ps += __shfl_xor(ps, 16, 64);
        ps += __shfl_xor(ps, 32, 64);
        float* lLw = (float*)myP;   // P dead, reuse (wave-private)
        if (quad == 0) lLw[l16] = ps;
        f32x4 lv = *(const f32x4*)&lLw[quad * 4];
        f32x4 inv;
        #pragma unroll
        for (int r = 0; r < 4; ++r) inv[r] = 1.0f / lv[r];
        #pragma unroll
        for (int d = 0; d < 4; ++d)
            #pragma unroll
            for (int r = 0; r < 4; ++r) {
                int qrow = q0w + quad * 4 + r;
                int dd = d * 16 + l16;
                O[(size_t)(bb * SEQ + qrow) * DM + h * DKV + dd] = (ushort_t)f2bf(acc[d][r] * inv[r]);
            }
    }
}

// ---------------- Output projection: out = AO * Wob^T (all bf16) ----------------
// proj skeleton (R9-verified): tile 128(M) x 64(N), BK=32, wave tile 64x32,
// triple-buffered gload LDS + counted vmcnt. grid (16, 32) = 512 blocks = 2/CU.
__global__ __launch_bounds__(256) void oproj_kernel(
    const ushort_t* __restrict__ A, const ushort_t* __restrict__ B, float* __restrict__ out)
{
    __shared__ __align__(16) short lA[3][128 * 32];   // 3 x 8 KB
    __shared__ __align__(16) short lB[3][64 * 32];    // 3 x 4 KB

    const int t = threadIdx.x;
    const int lane = t & 63;
    const int wid = t >> 6;
    const int quad = lane >> 4, l16 = lane & 15;
    const int mh = wid >> 1, nh = wid & 1;   // wave: 64(M) x 32(N)
    const int Mb = blockIdx.y * 128;
    const int Nb = blockIdx.x * 64;

    f32x4 acc[4][2] = {};

    auto stage = [&](int buf, int k0) {
        #pragma unroll
        for (int i = 0; i < 2; ++i) {   // A: 32 rows per wave
            int rbase = wid * 32 + i * 16;
            int row = rbase + (lane >> 2);
            int gch = (lane & 3) ^ ((lane >> 3) & 3);
            gload_lds16(A + (size_t)(Mb + row) * DM + k0 + gch * 8, &lA[buf][rbase * 32]);
        }
        {   // B: 16 rows per wave
            int rbase = wid * 16;
            int row = rbase + (lane >> 2);
            int gch = (lane & 3) ^ ((lane >> 3) & 3);
            gload_lds16(B + (size_t)(Nb + row) * DM + k0 + gch * 8, &lB[buf][rbase * 32]);
        }
    };

    stage(0, 0);
    stage(1, 32);

    for (int kt = 0; kt < 32; ++kt) {
        const int cur = kt % 3;
        if (kt == 31) asm volatile("s_waitcnt vmcnt(0)" ::: "memory");
        else          asm volatile("s_waitcnt vmcnt(3)" ::: "memory");
        __builtin_amdgcn_s_barrier();
        if (kt < 30) stage((kt + 2) % 3, kt * 32 + 64);

        bf16x8 a[4], b[2];
        #pragma unroll
        for (int mt = 0; mt < 4; ++mt) {
            int row = mh * 64 + mt * 16 + l16;
            int slot = quad ^ ((l16 >> 1) & 3);
            a[mt] = *(const bf16x8*)&lA[cur][row * 32 + slot * 8];
        }
        #pragma unroll
        for (int nt = 0; nt < 2; ++nt) {
            int row = nh * 32 + nt * 16 + l16;
            int slot = quad ^ ((l16 >> 1) & 3);
            b[nt] = *(const bf16x8*)&lB[cur][row * 32 + slot * 8];
        }
        __builtin_amdgcn_s_setprio(1);
        #pragma unroll
        for (int mt = 0; mt < 4; ++mt)
            #pragma unroll
            for (int nt = 0; nt < 2; ++nt)
                acc[mt][nt] = __builtin_amdgcn_mfma_f32_16x16x32_bf16(a[mt], b[nt], acc[mt][nt], 0, 0, 0);
        __builtin_amdgcn_s_setprio(0);
    }

    #pragma unroll
    for (int mt = 0; mt < 4; ++mt)
        #pragma unroll
        for (int nt = 0; nt < 2; ++nt)
            #pragma unroll
            for (int r = 0; r < 4; ++r) {
                int row = Mb + mh * 64 + mt * 16 + quad * 4 + r;
                int col = Nb + nh * 32 + nt * 16 + l16;
                out[(size_t)row * DM + col] = acc[mt][nt][r];
            }
}

extern "C" void kernel_launch(void* const* d_in, const int* in_sizes, int n_in,
                              void* d_out, int out_size, void* d_ws, size_t ws_size,
                              hipStream_t stream) {
    const float* x  = (const float*)d_in[0];
    const float* wq = (const float*)d_in[1];
    const float* wk = (const float*)d_in[2];
    const float* wv = (const float*)d_in[3];
    const float* wo = (const float*)d_in[4];
    const int* tokpos = (const int*)d_in[5];
    float* out = (float*)d_out;

    // Memory map (4-kernel graph; Wob de-aliased from Qg so wo-convert rides prep):
    //  ws[0:8M)    cos/sin + Wqkv (live prep->proj) -> AO (written by attn)
    //  ws[8:16M)   Qg (live through attn)
    //  ws[16:24M)  Kg (live through attn)
    //  ws[24:26M)  Wob (written by prep, read by oproj — untouched in between)
    //  d_out[0:8M)  xb (dead after proj; oproj overwrites with out)
    //  d_out[8:16M) Vt (dead after attn; oproj overwrites with out — oproj is last)
    char* ws = (char*)d_ws;
    float* cos_t    = (float*)ws;                          // 256 KB
    float* sin_t    = (float*)(ws + 256 * 1024);           // 256 KB
    ushort_t* Wqkv  = (ushort_t*)(ws + 512 * 1024);        // 6 MB
    ushort_t* AO    = (ushort_t*)ws;                       // 8 MB (aliases the above)
    ushort_t* Qg    = (ushort_t*)(ws + (size_t)8  * 1024 * 1024);  // 8 MB
    ushort_t* Kg    = (ushort_t*)(ws + (size_t)16 * 1024 * 1024);  // 8 MB
    ushort_t* Wob   = (ushort_t*)(ws + (size_t)24 * 1024 * 1024);  // 2 MB
    ushort_t* xb    = (ushort_t*)d_out;                            // 8 MB scratch
    ushort_t* Vt    = (ushort_t*)((char*)d_out + (size_t)8 * 1024 * 1024);  // 8 MB scratch

    prep_kernel<<<4352, 256, 0, stream>>>(x, wq, wk, wv, wo, Wqkv, xb, Wob, cos_t, sin_t);
    proj_qkv_kernel<<<dim3(3 * DM / 256, MTOT / 256), 512, 0, stream>>>(
        xb, Wqkv, cos_t, sin_t, tokpos, Qg, Kg, Vt);
    attn_kernel<<<dim3(SEQ / 128, 32), 256, 0, stream>>>(Qg, Kg, Vt, AO);
    oproj_kernel<<<dim3(DM / 64, MTOT / 128), 256, 0, stream>>>(AO, Wob, out);
}

// Round 18
// 193.127 us; speedup vs baseline: 1.0537x; 1.0257x over previous
//
#include <hip/hip_runtime.h>
#include <hip/hip_bf16.h>
#include <math.h>

#define SEQ 2048
#define DM 1024
#define NH 16
#define DKV 64
#define MTOT 4096   /* BATCH*SEQ */
#define PST2 72     /* P-tile LDS row stride in shorts (64 + 8 pad) */

typedef __attribute__((ext_vector_type(8))) short bf16x8;
typedef __attribute__((ext_vector_type(4))) short s16x4;
typedef __attribute__((ext_vector_type(4))) float f32x4;
typedef unsigned short ushort_t;

__device__ __forceinline__ short f2bf(float f) {
    union { float f; unsigned u; } v; v.f = f;
    unsigned r = v.u + 0x7fffu + ((v.u >> 16) & 1u);
    return (short)(r >> 16);
}

__device__ __forceinline__ bf16x8 cvt8(f32x4 a, f32x4 b) {
    union { __hip_bfloat162 h[4]; bf16x8 v; } u;
    u.h[0] = __float22bfloat162_rn(float2{a[0], a[1]});
    u.h[1] = __float22bfloat162_rn(float2{a[2], a[3]});
    u.h[2] = __float22bfloat162_rn(float2{b[0], b[1]});
    u.h[3] = __float22bfloat162_rn(float2{b[2], b[3]});
    return u.v;
}

__device__ __forceinline__ s16x4 cvt4(float a, float b, float c, float d) {
    union { __hip_bfloat162 h[2]; s16x4 v; } u;
    u.h[0] = __float22bfloat162_rn(float2{a, b});
    u.h[1] = __float22bfloat162_rn(float2{c, d});
    return u.v;
}

// async global->LDS, 16B per lane. LDS dest = wave-uniform base + lane*16.
__device__ __forceinline__ void gload_lds16(const void* g, void* l) {
    __builtin_amdgcn_global_load_lds(
        (const __attribute__((address_space(1))) unsigned int*)g,
        (__attribute__((address_space(3))) unsigned int*)l, 16, 0, 0);
}

// ---------------- fused prep: RoPE tables + wo + Wqkv fuse + x convert, one launch ----------------
// blocks [0,256): cos/sin tables (fp32)
// blocks [256,768): Wob = bf16(wo)   (de-aliased from Qg -> rides prep; 4-kernel graph, R11-verified)
// blocks [768,2304): Wqkv[3072][1024] = bf16(wq|wk|wv)
// blocks [2304,4352): xb = bf16(x)
__global__ void prep_kernel(const float* __restrict__ x,
                            const float* __restrict__ wq, const float* __restrict__ wk,
                            const float* __restrict__ wv, const float* __restrict__ wo,
                            ushort_t* __restrict__ Wqkv, ushort_t* __restrict__ xb,
                            ushort_t* __restrict__ Wob,
                            float* __restrict__ cos_t, float* __restrict__ sin_t) {
    const int b = blockIdx.x;
    if (b < 256) {
        int tid = b * 256 + threadIdx.x;           // 0..65535
        int i = tid & 31, pos = tid >> 5;
        float freq = expf(-9.210340372f * (float)(2 * i) / 64.0f);
        float ang = (float)pos * freq;
        cos_t[tid] = cosf(ang);
        sin_t[tid] = sinf(ang);
    } else if (b < 768) {
        int tid = (b - 256) * 256 + threadIdx.x;   // 0..131071
        int off = tid * 8;
        f32x4 a = ((const f32x4*)(wo + off))[0];
        f32x4 c = ((const f32x4*)(wo + off))[1];
        *(bf16x8*)&Wob[off] = cvt8(a, c);
    } else if (b < 2304) {
        int tid = (b - 768) * 256 + threadIdx.x;   // 0..393215
        int z = tid >> 17;
        int off = (tid & 131071) * 8;
        const float* src = (z == 0) ? wq : (z == 1) ? wk : wv;
        f32x4 a = ((const f32x4*)(src + off))[0];
        f32x4 c = ((const f32x4*)(src + off))[1];
        *(bf16x8*)&Wqkv[(size_t)z * 1048576 + off] = cvt8(a, c);
    } else {
        int tid = (b - 2304) * 256 + threadIdx.x;  // 0..524287
        int off = tid * 8;
        f32x4 a = ((const f32x4*)(x + off))[0];
        f32x4 c = ((const f32x4*)(x + off))[1];
        *(bf16x8*)&xb[off] = cvt8(a, c);
    }
}

// ---------------- Fused QKV projection + RoPE + V-transpose: 256x256 tile, 8 waves ----------------
// R15 configuration, verbatim (best measured total: 193.3 us). 256(M) x 256(N),
// BK=64, 8 waves (2x4), wave tile 128x64 (8x4 frags), 2-buf dbuf with vmcnt(0)
// drain. In isolation this proj is 75.4 us (slower than R17's 52.5 counted-vmcnt
// variant) yet the R15 total beat R17's by 4.8 us via an unidentified downstream
// coupling — this rerun is the reproducibility test.
// grid (12, 16) = 192 blocks, 1/CU. Q pre-scaled by 1/8.
__global__ __launch_bounds__(512) void proj_qkv_kernel(
    const ushort_t* __restrict__ xb, const ushort_t* __restrict__ Wqkv,
    const float* __restrict__ cos_t, const float* __restrict__ sin_t,
    const int* __restrict__ tokpos,
    ushort_t* __restrict__ Qg, ushort_t* __restrict__ Kg, ushort_t* __restrict__ Vt)
{
    __shared__ __align__(16) short lA[2][256 * 64];   // 2 x 32 KB
    __shared__ __align__(16) short lB[2][256 * 64];   // 2 x 32 KB

    const int t = threadIdx.x;
    const int lane = t & 63;
    const int wid = t >> 6;                  // 0..7
    const int quad = lane >> 4, l16 = lane & 15;
    const int wm = wid >> 2, wn = wid & 3;   // wave tile 128(M) x 64(N)
    const int Mb = blockIdx.y * 256;
    const int NbG = blockIdx.x * 256;
    const int z = NbG >> 10;
    const int Nb = NbG & 1023;

    f32x4 acc[8][4] = {};

    // Stage K-tile kt into buf: A rows [Mb,Mb+256), B rows [NbG,NbG+256), 64 k-cols.
    // Per wave: 32 rows each of A and B, 4 instrs of 8 rows (64 lanes x 16B = 8x128B).
    // phys chunk (lane&7) holds logical chunk gch = (lane&7)^(row&7)  [zero-conflict].
    auto stage = [&](int kt, int buf) {
        const int k0 = kt * 64;
        #pragma unroll
        for (int j = 0; j < 4; ++j) {
            int rbase = wid * 32 + j * 8;
            int row = rbase + (lane >> 3);
            int gch = (lane & 7) ^ (row & 7);
            gload_lds16(xb + (size_t)(Mb + row) * DM + k0 + gch * 8, &lA[buf][rbase * 64]);
        }
        #pragma unroll
        for (int j = 0; j < 4; ++j) {
            int rbase = wid * 32 + j * 8;
            int row = rbase + (lane >> 3);
            int gch = (lane & 7) ^ (row & 7);
            gload_lds16(Wqkv + (size_t)(NbG + row) * DM + k0 + gch * 8, &lB[buf][rbase * 64]);
        }
    };

    stage(0, 0);

    for (int kt = 0; kt < 16; ++kt) {
        const int cur = kt & 1;
        // Drain: stage(kt)'s 8 per-wave loads landed. All waves' iter-(kt-1)
        // ds_reads completed before this barrier (compiler lgkmcnt before MFMA),
        // so staging kt+1 into buf cur^1 right after is race-free.
        asm volatile("s_waitcnt vmcnt(0)" ::: "memory");
        __builtin_amdgcn_s_barrier();
        if (kt < 15) stage(kt + 1, cur ^ 1);

        #pragma unroll
        for (int ks = 0; ks < 2; ++ks) {     // two 32-wide k-steps of BK=64
            bf16x8 a[8], b[4];
            #pragma unroll
            for (int mf = 0; mf < 8; ++mf) {
                int row = wm * 128 + mf * 16 + l16;
                int slot = (ks * 4 + quad) ^ (row & 7);
                a[mf] = *(const bf16x8*)&lA[cur][row * 64 + slot * 8];
            }
            #pragma unroll
            for (int nf = 0; nf < 4; ++nf) {
                int row = wn * 64 + nf * 16 + l16;
                int slot = (ks * 4 + quad) ^ (row & 7);
                b[nf] = *(const bf16x8*)&lB[cur][row * 64 + slot * 8];
            }
            __builtin_amdgcn_s_setprio(1);
            #pragma unroll
            for (int mf = 0; mf < 8; ++mf)
                #pragma unroll
                for (int nf = 0; nf < 4; ++nf)
                    acc[mf][nf] = __builtin_amdgcn_mfma_f32_16x16x32_bf16(a[mf], b[nf], acc[mf][nf], 0, 0, 0);
            __builtin_amdgcn_s_setprio(0);
        }
    }

    // Epilogue: identical per-fragment code as the verified 128x64 version, looped
    // over the 8x4 wave fragments. 256-tiles never straddle z-slices (256|1024)
    // or batch boundaries (256|2048), so z and bb are block-uniform.
    const int bb = Mb >> 11;
    if (z == 2) {
        #pragma unroll
        for (int mf = 0; mf < 8; ++mf) {
            const int s0 = (Mb + wm * 128 + mf * 16 + quad * 4) & (SEQ - 1);
            #pragma unroll
            for (int nf = 0; nf < 4; ++nf) {
                int col = Nb + wn * 64 + nf * 16 + l16;
                int h = col >> 6, d = col & 63;
                s16x4 pk;
                #pragma unroll
                for (int r = 0; r < 4; ++r) pk[r] = f2bf(acc[mf][nf][r]);
                *(s16x4*)&Vt[((size_t)(bb * NH + h) * DKV + d) * SEQ + s0] = pk;
            }
        }
    } else {
        ushort_t* dst = (z == 0) ? Qg : Kg;
        const float qscale = (z == 0) ? 0.125f : 1.0f;
        #pragma unroll
        for (int mf = 0; mf < 8; ++mf) {
            #pragma unroll
            for (int nf = 0; nf < 4; ++nf) {
                #pragma unroll
                for (int r = 0; r < 4; ++r) {
                    int row = Mb + wm * 128 + mf * 16 + quad * 4 + r;
                    int s = row & (SEQ - 1);
                    int col = Nb + wn * 64 + nf * 16 + l16;
                    int h = col >> 6, d = col & 63;
                    float val = acc[mf][nf][r];
                    float part = __shfl_xor(val, 1, 64);
                    int pos = tokpos[s];
                    int i = d >> 1;
                    float c = cos_t[pos * 32 + i];
                    float sn = sin_t[pos * 32 + i];
                    val = (d & 1) ? (val * c + part * sn) : (val * c - part * sn);
                    val *= qscale;
                    dst[((size_t)(bb * NH + h) * SEQ + s) * DKV + d] = (ushort_t)f2bf(val);
                }
            }
        }
    }
}

// ---------------- Causal flash attention: folded triangle, 128-k staging / 64-k compute ----------------
// R13 form (best-measured). Block handles q-tile pair (qt, 31-qt): 17 staged
// 128-tiles per pair, perfect balance. Per-wave half-skip drops fully-masked
// halves. LDS 73 KB -> 2 blocks/CU, 8 waves/CU.
__global__ __launch_bounds__(256, 2) void attn_kernel(
    const ushort_t* __restrict__ Q, const ushort_t* __restrict__ K,
    const ushort_t* __restrict__ Vt, ushort_t* __restrict__ O)
{
    __shared__ __align__(16) short lK[2][2][64 * 64];   // [buf][half] 32 KB
    __shared__ __align__(16) short lV[2][2][64 * 64];   // [buf][half] 32 KB (V^T: [d][k])
    __shared__ __align__(16) short lP[4][16 * PST2];    // 9 KB, wave-private quarters

    const int t = threadIdx.x;
    const int lane = t & 63;
    const int wid = t >> 6;                     // 0..3
    const int quad = lane >> 4, l16 = lane & 15;
    const int bh = blockIdx.y;
    const int bb = bh >> 4, h = bh & 15;

    const ushort_t* Qb = Q + (size_t)bh * SEQ * DKV;
    const ushort_t* Kb = K + (size_t)bh * SEQ * DKV;
    const ushort_t* Vtb = Vt + (size_t)bh * DKV * SEQ;
    short* myP = lP[wid];

    auto stage = [&](int kb, int buf) {
        #pragma unroll
        for (int hf = 0; hf < 2; ++hf) {
            #pragma unroll
            for (int j = 0; j < 2; ++j) {       // K half: 16 rows/wave, 8 rows/instr
                int rbase = wid * 16 + j * 8;
                int row = rbase + (lane >> 3);
                int gch = (lane & 7) ^ (row & 7);
                gload_lds16(Kb + (size_t)(kb + hf * 64 + row) * DKV + gch * 8,
                            &lK[buf][hf][rbase * 64]);
            }
            #pragma unroll
            for (int j = 0; j < 2; ++j) {       // V^T half: rows are d, 64 k-cols
                int rbase = wid * 16 + j * 8;
                int row = rbase + (lane >> 3);
                int gch = (lane & 7) ^ (row & 7);
                gload_lds16(Vtb + (size_t)row * SEQ + kb + hf * 64 + gch * 8,
                            &lV[buf][hf][rbase * 64]);
            }
        }
    };

    #pragma unroll 1
    for (int ph = 0; ph < 2; ++ph) {
        const int qt = ph ? (31 - (int)blockIdx.x) : (int)blockIdx.x;
        const int q0w = qt * 64 + wid * 16;
        const int nkt2 = (qt >> 1) + 1;         // 128-wide staged tiles

        bf16x8 bq[2];
        #pragma unroll
        for (int hq = 0; hq < 2; ++hq)
            bq[hq] = *(const bf16x8*)(Qb + (size_t)(q0w + l16) * DKV + hq * 32 + quad * 8);

        f32x4 acc[4] = {};
        float ps = 0.f;

        if (ph) __syncthreads();
        stage(0, 0);

        for (int kt2 = 0; kt2 < nkt2; ++kt2) {
            const int kb128 = kt2 * 128;
            __syncthreads();                    // drains stage(kt2)
            if (kt2 + 1 < nkt2) stage(kb128 + 128, (kt2 + 1) & 1);

            #pragma unroll
            for (int hf = 0; hf < 2; ++hf) {
                const int kbase = kb128 + hf * 64;
                if (kbase > q0w + 15) continue; // half fully beyond this wave's rows

                const short* bK = lK[kt2 & 1][hf];
                const short* bV = lV[kt2 & 1][hf];

                bf16x8 ak[4][2];
                #pragma unroll
                for (int mt = 0; mt < 4; ++mt)
                    #pragma unroll
                    for (int hh = 0; hh < 2; ++hh) {
                        int row = mt * 16 + l16;
                        int slot = (hh * 4 + quad) ^ (row & 7);
                        ak[mt][hh] = *(const bf16x8*)&bK[row * 64 + slot * 8];
                    }

                f32x4 st[4];
                __builtin_amdgcn_s_setprio(1);
                #pragma unroll
                for (int mt = 0; mt < 4; ++mt) {
                    f32x4 zz = {};
                    zz = __builtin_amdgcn_mfma_f32_16x16x32_bf16(ak[mt][0], bq[0], zz, 0, 0, 0);
                    zz = __builtin_amdgcn_mfma_f32_16x16x32_bf16(ak[mt][1], bq[1], zz, 0, 0, 0);
                    st[mt] = zz;
                }
                __builtin_amdgcn_s_setprio(0);

                if (kbase + 63 > q0w) {
                    #pragma unroll
                    for (int mt = 0; mt < 4; ++mt) {
                        float pv[4];
                        #pragma unroll
                        for (int r = 0; r < 4; ++r) {
                            int k_abs = kbase + mt * 16 + quad * 4 + r;
                            int q_abs = q0w + l16;
                            pv[r] = (k_abs > q_abs) ? 0.f : __expf(st[mt][r]);
                            ps += pv[r];
                        }
                        *(s16x4*)&myP[l16 * PST2 + mt * 16 + quad * 4] = cvt4(pv[0], pv[1], pv[2], pv[3]);
                    }
                } else {
                    #pragma unroll
                    for (int mt = 0; mt < 4; ++mt) {
                        float pv[4];
                        #pragma unroll
                        for (int r = 0; r < 4; ++r) {
                            pv[r] = __expf(st[mt][r]);
                            ps += pv[r];
                        }
                        *(s16x4*)&myP[l16 * PST2 + mt * 16 + quad * 4] = cvt4(pv[0], pv[1], pv[2], pv[3]);
                    }
                }

                bf16x8 ap[2];
                ap[0] = *(const bf16x8*)&myP[l16 * PST2 + quad * 8];
                ap[1] = *(const bf16x8*)&myP[l16 * PST2 + 32 + quad * 8];

                __builtin_amdgcn_s_setprio(1);
                #pragma unroll
                for (int d = 0; d < 4; ++d) {
                    int row = d * 16 + l16;
                    int slot0 = quad ^ (row & 7);
                    int slot1 = (4 + quad) ^ (row & 7);
                    bf16x8 bv0 = *(const bf16x8*)&bV[row * 64 + slot0 * 8];
                    bf16x8 bv1 = *(const bf16x8*)&bV[row * 64 + slot1 * 8];
                    acc[d] = __builtin_amdgcn_mfma_f32_16x16x32_bf16(ap[0], bv0, acc[d], 0, 0, 0);
                    acc[d] = __builtin_amdgcn_mfma_f32_16x16x32_bf16(ap[1], bv1, acc[d], 0, 0, 0);
                }
                __builtin_amdgcn_s_setprio(0);
            }
        }

        // epilogue (per wave)
        ps += __shfl_xor(ps, 16, 64);
        ps += __shfl_xor(ps, 32, 64);
        float* lLw = (float*)myP;   // P dead, reuse (wave-private)
        if (quad == 0) lLw[l16] = ps;
        f32x4 lv = *(const f32x4*)&lLw[quad * 4];
        f32x4 inv;
        #pragma unroll
        for (int r = 0; r < 4; ++r) inv[r] = 1.0f / lv[r];
        #pragma unroll
        for (int d = 0; d < 4; ++d)
            #pragma unroll
            for (int r = 0; r < 4; ++r) {
                int qrow = q0w + quad * 4 + r;
                int dd = d * 16 + l16;
                O[(size_t)(bb * SEQ + qrow) * DM + h * DKV + dd] = (ushort_t)f2bf(acc[d][r] * inv[r]);
            }
    }
}

// ---------------- Output projection: out = AO * Wob^T (all bf16) ----------------
// proj skeleton (R9-verified): tile 128(M) x 64(N), BK=32, wave tile 64x32,
// triple-buffered gload LDS + counted vmcnt. grid (16, 32) = 512 blocks = 2/CU.
__global__ __launch_bounds__(256) void oproj_kernel(
    const ushort_t* __restrict__ A, const ushort_t* __restrict__ B, float* __restrict__ out)
{
    __shared__ __align__(16) short lA[3][128 * 32];   // 3 x 8 KB
    __shared__ __align__(16) short lB[3][64 * 32];    // 3 x 4 KB

    const int t = threadIdx.x;
    const int lane = t & 63;
    const int wid = t >> 6;
    const int quad = lane >> 4, l16 = lane & 15;
    const int mh = wid >> 1, nh = wid & 1;   // wave: 64(M) x 32(N)
    const int Mb = blockIdx.y * 128;
    const int Nb = blockIdx.x * 64;

    f32x4 acc[4][2] = {};

    auto stage = [&](int buf, int k0) {
        #pragma unroll
        for (int i = 0; i < 2; ++i) {   // A: 32 rows per wave
            int rbase = wid * 32 + i * 16;
            int row = rbase + (lane >> 2);
            int gch = (lane & 3) ^ ((lane >> 3) & 3);
            gload_lds16(A + (size_t)(Mb + row) * DM + k0 + gch * 8, &lA[buf][rbase * 32]);
        }
        {   // B: 16 rows per wave
            int rbase = wid * 16;
            int row = rbase + (lane >> 2);
            int gch = (lane & 3) ^ ((lane >> 3) & 3);
            gload_lds16(B + (size_t)(Nb + row) * DM + k0 + gch * 8, &lB[buf][rbase * 32]);
        }
    };

    stage(0, 0);
    stage(1, 32);

    for (int kt = 0; kt < 32; ++kt) {
        const int cur = kt % 3;
        if (kt == 31) asm volatile("s_waitcnt vmcnt(0)" ::: "memory");
        else          asm volatile("s_waitcnt vmcnt(3)" ::: "memory");
        __builtin_amdgcn_s_barrier();
        if (kt < 30) stage((kt + 2) % 3, kt * 32 + 64);

        bf16x8 a[4], b[2];
        #pragma unroll
        for (int mt = 0; mt < 4; ++mt) {
            int row = mh * 64 + mt * 16 + l16;
            int slot = quad ^ ((l16 >> 1) & 3);
            a[mt] = *(const bf16x8*)&lA[cur][row * 32 + slot * 8];
        }
        #pragma unroll
        for (int nt = 0; nt < 2; ++nt) {
            int row = nh * 32 + nt * 16 + l16;
            int slot = quad ^ ((l16 >> 1) & 3);
            b[nt] = *(const bf16x8*)&lB[cur][row * 32 + slot * 8];
        }
        __builtin_amdgcn_s_setprio(1);
        #pragma unroll
        for (int mt = 0; mt < 4; ++mt)
            #pragma unroll
            for (int nt = 0; nt < 2; ++nt)
                acc[mt][nt] = __builtin_amdgcn_mfma_f32_16x16x32_bf16(a[mt], b[nt], acc[mt][nt], 0, 0, 0);
        __builtin_amdgcn_s_setprio(0);
    }

    #pragma unroll
    for (int mt = 0; mt < 4; ++mt)
        #pragma unroll
        for (int nt = 0; nt < 2; ++nt)
            #pragma unroll
            for (int r = 0; r < 4; ++r) {
                int row = Mb + mh * 64 + mt * 16 + quad * 4 + r;
                int col = Nb + nh * 32 + nt * 16 + l16;
                out[(size_t)row * DM + col] = acc[mt][nt][r];
            }
}

extern "C" void kernel_launch(void* const* d_in, const int* in_sizes, int n_in,
                              void* d_out, int out_size, void* d_ws, size_t ws_size,
                              hipStream_t stream) {
    const float* x  = (const float*)d_in[0];
    const float* wq = (const float*)d_in[1];
    const float* wk = (const float*)d_in[2];
    const float* wv = (const float*)d_in[3];
    const float* wo = (const float*)d_in[4];
    const int* tokpos = (const int*)d_in[5];
    float* out = (float*)d_out;

    // Memory map (4-kernel graph; Wob de-aliased from Qg so wo-convert rides prep):
    //  ws[0:8M)    cos/sin + Wqkv (live prep->proj) -> AO (written by attn)
    //  ws[8:16M)   Qg (live through attn)
    //  ws[16:24M)  Kg (live through attn)
    //  ws[24:26M)  Wob (written by prep, read by oproj — untouched in between)
    //  d_out[0:8M)  xb (dead after proj; oproj overwrites with out)
    //  d_out[8:16M) Vt (dead after attn; oproj overwrites with out — oproj is last)
    char* ws = (char*)d_ws;
    float* cos_t    = (float*)ws;                          // 256 KB
    float* sin_t    = (float*)(ws + 256 * 1024);           // 256 KB
    ushort_t* Wqkv  = (ushort_t*)(ws + 512 * 1024);        // 6 MB
    ushort_t* AO    = (ushort_t*)ws;                       // 8 MB (aliases the above)
    ushort_t* Qg    = (ushort_t*)(ws + (size_t)8  * 1024 * 1024);  // 8 MB
    ushort_t* Kg    = (ushort_t*)(ws + (size_t)16 * 1024 * 1024);  // 8 MB
    ushort_t* Wob   = (ushort_t*)(ws + (size_t)24 * 1024 * 1024);  // 2 MB
    ushort_t* xb    = (ushort_t*)d_out;                            // 8 MB scratch
    ushort_t* Vt    = (ushort_t*)((char*)d_out + (size_t)8 * 1024 * 1024);  // 8 MB scratch

    prep_kernel<<<4352, 256, 0, stream>>>(x, wq, wk, wv, wo, Wqkv, xb, Wob, cos_t, sin_t);
    proj_qkv_kernel<<<dim3(3 * DM / 256, MTOT / 256), 512, 0, stream>>>(
        xb, Wqkv, cos_t, sin_t, tokpos, Qg, Kg, Vt);
    attn_kernel<<<dim3(SEQ / 128, 32), 256, 0, stream>>>(Qg, Kg, Vt, AO);
    oproj_kernel<<<dim3(DM / 64, MTOT / 128), 256, 0, stream>>>(AO, Wob, out);
}